// Round 1
// baseline (429.231 us; speedup 1.0000x reference)
//
#include <hip/hip_runtime.h>

typedef unsigned short u16;
typedef unsigned int   u32;
typedef __attribute__((ext_vector_type(8))) short short8;
typedef __attribute__((ext_vector_type(4))) float f32x4;
typedef __attribute__((ext_vector_type(4))) u16   u16x4;

#define NB 4
#define SL 4096
#define DM 1024
#define NH 16
#define DK 64

__device__ __forceinline__ u16 f2bf(float f) {
  u32 u = __builtin_bit_cast(u32, f);
  u = (u + 0x7fffu + ((u >> 16) & 1u)) >> 16;
  return (u16)u;
}
__device__ __forceinline__ float bf2f(u16 v) {
  u32 u = ((u32)v) << 16;
  return __builtin_bit_cast(float, u);
}
__device__ __forceinline__ float eluP1(float x) {
  return x > 0.f ? x + 1.f : __expf(x);
}
__device__ __forceinline__ void gll16(const u16* g, u16* l) {
  __builtin_amdgcn_global_load_lds((const __attribute__((address_space(1))) void*)g,
                                   (__attribute__((address_space(3))) void*)l, 16, 0, 0);
}

// ---------------- fp32 -> bf16 conversion ----------------
__global__ void cvt_f32_bf16(const float* __restrict__ in, u16* __restrict__ out, int n4) {
  int i = blockIdx.x * 256 + threadIdx.x;
  if (i < n4) {
    f32x4 f = *(const f32x4*)(in + (size_t)i * 4);
    u16x4 o = { f2bf(f[0]), f2bf(f[1]), f2bf(f[2]), f2bf(f[3]) };
    *(u16x4*)(out + (size_t)i * 4) = o;
  }
}

// ---------------- big GEMM: C = act(A @ W^T + bias) ----------------
// A: [M=16384][K=1024] bf16 row-major, W: [N=1024][K=1024] bf16 row-major.
// ORIENT=0: MFMA A-op = X rows  -> D rows = l   (used for transposed store)
// ORIENT=1: MFMA A-op = W rows  -> D rows = n   (used for [l][n] store)
// OMODE: 0 = bf16 normal [m][n], 1 = bf16 transposed [b][n][l], 2 = f32 normal
template<int ORIENT, int ACT, int OMODE>
__global__ __launch_bounds__(256) void gemm_bt(const u16* __restrict__ A,
                                               const u16* __restrict__ W,
                                               const float* __restrict__ bias,
                                               void* __restrict__ outp) {
  const int K = 1024;
  const int tile_m = blockIdx.x >> 3;   // 128 tiles of M
  const int tile_n = blockIdx.x & 7;    // 8 tiles of N
  const int tid = threadIdx.x, lane = tid & 63, wv = tid >> 6;
  const int i16 = lane & 15, q = lane >> 4;
  const int waveR = wv >> 1, waveC = wv & 1;

  __shared__ u16 Xs[128 * 32];
  __shared__ u16 Ws[128 * 32];

  // staging: wave wv instance j covers tile rows wv*32+j*16 .. +15
  // lane -> row offset lane>>2, chunk position lane&3 (8 bf16 per chunk)
  // XOR swizzle: position p of row r holds global k-chunk p ^ ((r>>1)&3)
  const int rbase = wv * 32 + (lane >> 2);
  const int kc = (lane & 3) ^ ((rbase >> 1) & 3);
  const u16* Ag = A + (size_t)(tile_m * 128 + rbase) * K + kc * 8;
  const u16* Wg = W + (size_t)(tile_n * 128 + rbase) * K + kc * 8;
  u16* XsB = Xs + wv * 1024;  // +j*512 elems; HW adds lane*16B
  u16* WsB = Ws + wv * 1024;

  f32x4 acc[4][4] = {};

  for (int k0 = 0; k0 < K; k0 += 32) {
    __syncthreads();
    gll16(Ag + k0,           XsB);
    gll16(Ag + k0 + 16 * K,  XsB + 512);
    gll16(Wg + k0,           WsB);
    gll16(Wg + k0 + 16 * K,  WsB + 512);
    __syncthreads();

    const u16* aT = ORIENT ? Ws : Xs;
    const u16* bT = ORIENT ? Xs : Ws;
    short8 af[4], bfr[4];
#pragma unroll
    for (int t = 0; t < 4; t++) {
      int m = waveR * 64 + t * 16 + i16;
      af[t] = *(const short8*)(aT + m * 32 + ((q ^ ((m >> 1) & 3)) << 3));
    }
#pragma unroll
    for (int u = 0; u < 4; u++) {
      int m = waveC * 64 + u * 16 + i16;
      bfr[u] = *(const short8*)(bT + m * 32 + ((q ^ ((m >> 1) & 3)) << 3));
    }
#pragma unroll
    for (int t = 0; t < 4; t++)
#pragma unroll
      for (int u = 0; u < 4; u++)
        acc[t][u] = __builtin_amdgcn_mfma_f32_16x16x32_bf16(af[t], bfr[u], acc[t][u], 0, 0, 0);
  }

  // epilogue
#pragma unroll
  for (int t = 0; t < 4; t++) {
#pragma unroll
    for (int u = 0; u < 4; u++) {
      if (OMODE == 1) {
        // ORIENT==0: D rows = l (t, quad*4+reg), cols = n (u, i16)
        int n_glb = tile_n * 128 + waveC * 64 + u * 16 + i16;
        int m_row = tile_m * 128 + waveR * 64 + t * 16 + q * 4;
        int bI = m_row >> 12, l = m_row & 4095;
        float bsc = bias[n_glb];
        u16x4 o;
#pragma unroll
        for (int r = 0; r < 4; r++) {
          float vv = acc[t][u][r] + bsc;
          if (ACT) vv = eluP1(vv);
          o[r] = f2bf(vv);
        }
        *(u16x4*)((u16*)outp + (size_t)bI * (DM * SL) + (size_t)n_glb * SL + l) = o;
      } else {
        // ORIENT==1: D rows = n (t, quad*4+reg), cols = l (u, i16)
        int n_glb = tile_n * 128 + waveR * 64 + t * 16 + q * 4;
        int m_glb = tile_m * 128 + waveC * 64 + u * 16 + i16;
        f32x4 b4 = *(const f32x4*)(bias + n_glb);
        if (OMODE == 2) {
          f32x4 o;
#pragma unroll
          for (int r = 0; r < 4; r++) {
            float vv = acc[t][u][r] + b4[r];
            if (ACT) vv = eluP1(vv);
            o[r] = vv;
          }
          *(f32x4*)((float*)outp + (size_t)m_glb * DM + n_glb) = o;
        } else {
          u16x4 o;
#pragma unroll
          for (int r = 0; r < 4; r++) {
            float vv = acc[t][u][r] + b4[r];
            if (ACT) vv = eluP1(vv);
            o[r] = f2bf(vv);
          }
          *(u16x4*)((u16*)outp + (size_t)m_glb * DM + n_glb) = o;
        }
      }
    }
  }
}

// ---------------- KV partial: KV[d][m] = sum_l phiKT[d][l]*vT[m][l] ----------------
// grid 256: block = (bh, chunk of L/4); 4 waves, each covers 256 l.
__global__ __launch_bounds__(256) void kv_partial(const u16* __restrict__ phiKT,
                                                  const u16* __restrict__ vT,
                                                  float* __restrict__ part) {
  int bh = blockIdx.x >> 2, chunk = blockIdx.x & 3;
  int tid = threadIdx.x, lane = tid & 63, wv = tid >> 6;
  int i16 = lane & 15, q = lane >> 4;
  const u16* Ab = phiKT + (size_t)bh * DK * SL;
  const u16* Bb = vT + (size_t)bh * DK * SL;
  int l0 = (chunk * 4 + wv) * 256;
  f32x4 acc[4][4] = {};
  for (int kk = 0; kk < 256; kk += 32) {
    int col = l0 + kk + q * 8;
    short8 af[4], bfr[4];
#pragma unroll
    for (int t = 0; t < 4; t++) af[t] = *(const short8*)(Ab + (size_t)(t * 16 + i16) * SL + col);
#pragma unroll
    for (int u = 0; u < 4; u++) bfr[u] = *(const short8*)(Bb + (size_t)(u * 16 + i16) * SL + col);
#pragma unroll
    for (int t = 0; t < 4; t++)
#pragma unroll
      for (int u = 0; u < 4; u++)
        acc[t][u] = __builtin_amdgcn_mfma_f32_16x16x32_bf16(af[t], bfr[u], acc[t][u], 0, 0, 0);
  }
  __shared__ float red[4][64][64];  // 64KB
#pragma unroll
  for (int t = 0; t < 4; t++)
#pragma unroll
    for (int u = 0; u < 4; u++)
#pragma unroll
      for (int r = 0; r < 4; r++)
        red[wv][t * 16 + q * 4 + r][u * 16 + i16] = acc[t][u][r];
  __syncthreads();
  int d = tid >> 2, mg = (tid & 3) * 16;
  for (int mm = 0; mm < 16; mm++) {
    int m = mg + mm;
    float s = red[0][d][m] + red[1][d][m] + red[2][d][m] + red[3][d][m];
    part[((size_t)(chunk * 64 + bh) * 64 + d) * 64 + m] = s;
  }
}

// ---------------- K_sum partials ----------------
__global__ __launch_bounds__(256) void ksum_partial(const u16* __restrict__ phiKT,
                                                    float* __restrict__ ksumP) {
  int bh = blockIdx.x >> 2, qt = blockIdx.x & 3;
  int tid = threadIdx.x;
  int d = tid >> 2, sub = tid & 3;
  const u16* p = phiKT + (size_t)(bh * 64 + d) * SL + qt * 1024 + sub * 256;
  float s = 0.f;
  for (int i = 0; i < 256; i += 8) {
    short8 v8 = *(const short8*)(p + i);
#pragma unroll
    for (int j = 0; j < 8; j++) s += bf2f((u16)v8[j]);
  }
  __shared__ float lds[64][4];
  lds[d][sub] = s;
  __syncthreads();
  if (tid < 64)
    ksumP[qt * 4096 + bh * 64 + tid] = lds[tid][0] + lds[tid][1] + lds[tid][2] + lds[tid][3];
}

// ---------------- finalize: KVt (bf16, transposed [m][d]) + Ksum ----------------
__global__ __launch_bounds__(256) void kv_finalize(const float* __restrict__ part,
                                                   const float* __restrict__ ksumP,
                                                   u16* __restrict__ KVt,
                                                   float* __restrict__ Ksum) {
  int bh = blockIdx.x, tid = threadIdx.x;
  for (int e = tid; e < 4096; e += 256) {
    int d = e >> 6, m = e & 63;
    float s = part[((size_t)(0 * 64 + bh) * 64 + d) * 64 + m]
            + part[((size_t)(1 * 64 + bh) * 64 + d) * 64 + m]
            + part[((size_t)(2 * 64 + bh) * 64 + d) * 64 + m]
            + part[((size_t)(3 * 64 + bh) * 64 + d) * 64 + m];
    KVt[(size_t)bh * 4096 + m * 64 + d] = f2bf(s);
  }
  if (tid < 64) {
    float s = ksumP[0 * 4096 + bh * 64 + tid] + ksumP[1 * 4096 + bh * 64 + tid]
            + ksumP[2 * 4096 + bh * 64 + tid] + ksumP[3 * 4096 + bh * 64 + tid];
    Ksum[bh * 64 + tid] = s;
  }
}

// ---------------- V_new = (phi_q @ KV) * Z ----------------
// grid 2048: block = (bh, ltile of 128). 4 waves: waveM=wv&1 (m half 32), waveL=wv>>1 (l half 64).
__global__ __launch_bounds__(256) void vnew_kernel(const u16* __restrict__ phiq,
                                                   const u16* __restrict__ KVt,
                                                   const float* __restrict__ Ksum,
                                                   u16* __restrict__ Vnew) {
  int bh = blockIdx.x >> 5, lt = blockIdx.x & 31;
  int b = bh >> 4, h = bh & 15;
  int tid = threadIdx.x, lane = tid & 63, wv = tid >> 6;
  int i16 = lane & 15, q = lane >> 4;
  int waveM = wv & 1, waveL = wv >> 1;

  __shared__ float Zs[128];
  __shared__ float Pp[128][2];
  {
    int l = tid >> 1, half = tid & 1;
    const u16* pr = phiq + (size_t)(b * SL + lt * 128 + l) * DM + h * 64 + half * 32;
    float s = 0.f;
    for (int i = 0; i < 32; i += 8) {
      short8 v8 = *(const short8*)(pr + i);
#pragma unroll
      for (int j = 0; j < 8; j++) s += bf2f((u16)v8[j]) * Ksum[bh * 64 + half * 32 + i + j];
    }
    Pp[l][half] = s;
  }
  __syncthreads();
  if (tid < 128) Zs[tid] = 1.0f / (Pp[tid][0] + Pp[tid][1] + 1e-5f);
  __syncthreads();

  f32x4 acc[2][4] = {};
#pragma unroll
  for (int step = 0; step < 2; step++) {
    int d0 = step * 32 + q * 8;
    short8 af[2], bfr[4];
#pragma unroll
    for (int t = 0; t < 2; t++) {
      int m = waveM * 32 + t * 16 + i16;
      af[t] = *(const short8*)(KVt + (size_t)bh * 4096 + m * 64 + d0);
    }
#pragma unroll
    for (int u = 0; u < 4; u++) {
      int l = lt * 128 + waveL * 64 + u * 16 + i16;
      bfr[u] = *(const short8*)(phiq + (size_t)(b * SL + l) * DM + h * 64 + d0);
    }
#pragma unroll
    for (int t = 0; t < 2; t++)
#pragma unroll
      for (int u = 0; u < 4; u++)
        acc[t][u] = __builtin_amdgcn_mfma_f32_16x16x32_bf16(af[t], bfr[u], acc[t][u], 0, 0, 0);
  }

#pragma unroll
  for (int t = 0; t < 2; t++) {
#pragma unroll
    for (int u = 0; u < 4; u++) {
      int l_loc = waveL * 64 + u * 16 + i16;
      float z = Zs[l_loc];
      int n = h * 64 + waveM * 32 + t * 16 + q * 4;
      u16x4 o;
#pragma unroll
      for (int r = 0; r < 4; r++) o[r] = f2bf(acc[t][u][r] * z);
      *(u16x4*)(Vnew + (size_t)(b * SL + lt * 128 + l_loc) * DM + n) = o;
    }
  }
}

extern "C" void kernel_launch(void* const* d_in, const int* in_sizes, int n_in,
                              void* d_out, int out_size, void* d_ws, size_t ws_size,
                              hipStream_t stream) {
  const float* Qf = (const float*)d_in[0];
  const float* WQ = (const float*)d_in[1];
  const float* bQ = (const float*)d_in[2];
  const float* WK = (const float*)d_in[3];
  const float* bK = (const float*)d_in[4];
  const float* WV = (const float*)d_in[5];
  const float* bV = (const float*)d_in[6];
  const float* WO = (const float*)d_in[7];
  const float* bO = (const float*)d_in[8];

  const size_t MB = 1024ull * 1024ull;
  char* ws = (char*)d_ws;
  u16* Qbf   = (u16*)(ws + 0);          // 32MB; reused as Vnew after QKV gemms
  u16* Vnew  = (u16*)(ws + 0);
  u16* Wqbf  = (u16*)(ws + 32 * MB);    // 2MB
  u16* Wkbf  = (u16*)(ws + 34 * MB);
  u16* Wvbf  = (u16*)(ws + 36 * MB);
  u16* Wobf  = (u16*)(ws + 38 * MB);
  u16* phiq  = (u16*)(ws + 40 * MB);    // 32MB
  u16* phiKT = (u16*)(ws + 72 * MB);    // 32MB [b][h][d][l]
  u16* vT    = (u16*)(ws + 104 * MB);   // 32MB [b][h][m][l]
  u16* KVt   = (u16*)(ws + 136 * MB);   // 512KB [bh][m][d]
  float* Ksum  = (float*)(ws + 137 * MB);  // 16KB
  float* part  = (float*)(ws + 138 * MB);  // 4MB
  float* ksumP = (float*)(ws + 142 * MB);  // 64KB

  // convert inputs to bf16
  cvt_f32_bf16<<<16384, 256, 0, stream>>>(Qf, Qbf, 4194304);
  cvt_f32_bf16<<<1024, 256, 0, stream>>>(WQ, Wqbf, 262144);
  cvt_f32_bf16<<<1024, 256, 0, stream>>>(WK, Wkbf, 262144);
  cvt_f32_bf16<<<1024, 256, 0, stream>>>(WV, Wvbf, 262144);
  cvt_f32_bf16<<<1024, 256, 0, stream>>>(WO, Wobf, 262144);

  // projections
  gemm_bt<1, 1, 0><<<1024, 256, 0, stream>>>(Qbf, Wqbf, bQ, phiq);   // phi_q [b*l][n]
  gemm_bt<0, 1, 1><<<1024, 256, 0, stream>>>(Qbf, Wkbf, bK, phiKT);  // phi_k^T [b][n][l]
  gemm_bt<0, 0, 1><<<1024, 256, 0, stream>>>(Qbf, Wvbf, bV, vT);     // v^T [b][n][l]

  // KV + K_sum
  kv_partial<<<256, 256, 0, stream>>>(phiKT, vT, part);
  ksum_partial<<<256, 256, 0, stream>>>(phiKT, ksumP);
  kv_finalize<<<64, 256, 0, stream>>>(part, ksumP, KVt, Ksum);

  // V_new
  vnew_kernel<<<2048, 256, 0, stream>>>(phiq, KVt, Ksum, Vnew);

  // output projection (fp32 out)
  gemm_bt<1, 0, 2><<<1024, 256, 0, stream>>>(Vnew, Wobf, bO, (float*)d_out);
}

// Round 2
// 383.529 us; speedup vs baseline: 1.1192x; 1.1192x over previous
//
#include <hip/hip_runtime.h>

typedef unsigned short u16;
typedef unsigned int   u32;
typedef __attribute__((ext_vector_type(8))) short short8;
typedef __attribute__((ext_vector_type(4))) float f32x4;
typedef __attribute__((ext_vector_type(4))) u16   u16x4;

#define NB 4
#define SL 4096
#define DM 1024
#define NH 16
#define DK 64

__device__ __forceinline__ u16 f2bf(float f) {
  u32 u = __builtin_bit_cast(u32, f);
  u = (u + 0x7fffu + ((u >> 16) & 1u)) >> 16;
  return (u16)u;
}
__device__ __forceinline__ float bf2f(u16 v) {
  u32 u = ((u32)v) << 16;
  return __builtin_bit_cast(float, u);
}
__device__ __forceinline__ float eluP1(float x) {
  return x > 0.f ? x + 1.f : __expf(x);
}
__device__ __forceinline__ void gll16(const u16* g, u16* l) {
  __builtin_amdgcn_global_load_lds((const __attribute__((address_space(1))) void*)g,
                                   (__attribute__((address_space(3))) void*)l, 16, 0, 0);
}

// ---------------- fp32 -> bf16 conversion (Q) ----------------
__global__ void cvt_f32_bf16(const float* __restrict__ in, u16* __restrict__ out, int n4) {
  int i = blockIdx.x * 256 + threadIdx.x;
  if (i < n4) {
    f32x4 f = *(const f32x4*)(in + (size_t)i * 4);
    u16x4 o = { f2bf(f[0]), f2bf(f[1]), f2bf(f[2]), f2bf(f[3]) };
    *(u16x4*)(out + (size_t)i * 4) = o;
  }
}

// ---------------- weight conversion: pack WQ|WK|WV contiguous, plus WO ----------------
__global__ void cvt_w(const float* __restrict__ WQ, const float* __restrict__ WK,
                      const float* __restrict__ WV, const float* __restrict__ WO,
                      u16* __restrict__ Wqkv, u16* __restrict__ Wobf) {
  int r = blockIdx.x >> 10;
  int i = (blockIdx.x & 1023) * 256 + threadIdx.x;
  const float* src = r == 0 ? WQ : r == 1 ? WK : r == 2 ? WV : WO;
  u16* dst = (r == 3) ? Wobf : Wqkv + (size_t)r * 1048576;
  f32x4 f = *(const f32x4*)(src + (size_t)i * 4);
  u16x4 o = { f2bf(f[0]), f2bf(f[1]), f2bf(f[2]), f2bf(f[3]) };
  *(u16x4*)(dst + (size_t)i * 4) = o;
}

__global__ void pack_bias(const float* __restrict__ bQ, const float* __restrict__ bK,
                          const float* __restrict__ bV, float* __restrict__ biasQKV) {
  int i = blockIdx.x * 256 + threadIdx.x;  // 0..3071
  float v = (i < 1024) ? bQ[i] : (i < 2048) ? bK[i - 1024] : bV[i - 2048];
  biasQKV[i] = v;
}

// ---------------- fused QKV GEMM ----------------
// A: Qbf [16384][1024]. Wqkv: [3072][1024]. tile_n 0..23; region = tile_n>>3.
// region 0 (Q): D rows = n -> store phi_q [b*l][n] bf16, elu+1
// region 1 (K): D rows = l -> store phiKT [b][n][l] bf16, elu+1
// region 2 (V): D rows = l -> store vT   [b][n][l] bf16, no act
__global__ __launch_bounds__(256) void gemm_qkv(const u16* __restrict__ A,
                                                const u16* __restrict__ Wqkv,
                                                const float* __restrict__ biasQKV,
                                                u16* __restrict__ phiq,
                                                u16* __restrict__ phiKT,
                                                u16* __restrict__ vT) {
  const int K = 1024;
  // XCD-aware swizzle: xcd rectangle = 32 tile_m x 12 tile_n
  const int bId = blockIdx.x;
  const int xcd = bId & 7, s = bId >> 3;        // s 0..383
  const int xm = xcd >> 1, xn = xcd & 1;
  const int tm_l = s / 12, tn_l = s - tm_l * 12;
  const int tile_m = xm * 32 + tm_l;            // 0..127
  const int tile_n = xn * 12 + tn_l;            // 0..23
  const int region = tile_n >> 3;               // 0=Q,1=K,2=V

  const int tid = threadIdx.x, lane = tid & 63, wv = tid >> 6;
  const int i16 = lane & 15, q = lane >> 4;
  const int waveR = wv >> 1, waveC = wv & 1;

  __shared__ u16 Xs[128 * 32];
  __shared__ u16 Ws[128 * 32];

  const int rbase = wv * 32 + (lane >> 2);
  const int kc = (lane & 3) ^ ((rbase >> 1) & 3);
  const u16* Ag = A + (size_t)(tile_m * 128 + rbase) * K + kc * 8;
  const u16* Wg = Wqkv + (size_t)(tile_n * 128 + rbase) * K + kc * 8;
  u16* XsB = Xs + wv * 1024;
  u16* WsB = Ws + wv * 1024;

  f32x4 acc[4][4] = {};

  const u16* aT = (region == 0) ? Ws : Xs;
  const u16* bT = (region == 0) ? Xs : Ws;

  for (int k0 = 0; k0 < K; k0 += 32) {
    __syncthreads();
    gll16(Ag + k0,          XsB);
    gll16(Ag + k0 + 16 * K, XsB + 512);
    gll16(Wg + k0,          WsB);
    gll16(Wg + k0 + 16 * K, WsB + 512);
    __syncthreads();

    short8 af[4], bfr[4];
#pragma unroll
    for (int t = 0; t < 4; t++) {
      int m = waveR * 64 + t * 16 + i16;
      af[t] = *(const short8*)(aT + m * 32 + ((q ^ ((m >> 1) & 3)) << 3));
    }
#pragma unroll
    for (int u = 0; u < 4; u++) {
      int m = waveC * 64 + u * 16 + i16;
      bfr[u] = *(const short8*)(bT + m * 32 + ((q ^ ((m >> 1) & 3)) << 3));
    }
#pragma unroll
    for (int t = 0; t < 4; t++)
#pragma unroll
      for (int u = 0; u < 4; u++)
        acc[t][u] = __builtin_amdgcn_mfma_f32_16x16x32_bf16(af[t], bfr[u], acc[t][u], 0, 0, 0);
  }

  if (region == 0) {
#pragma unroll
    for (int t = 0; t < 4; t++) {
#pragma unroll
      for (int u = 0; u < 4; u++) {
        int n_glb = tile_n * 128 + waveR * 64 + t * 16 + q * 4;  // 0..1023
        int m_glb = tile_m * 128 + waveC * 64 + u * 16 + i16;
        f32x4 b4 = *(const f32x4*)(biasQKV + n_glb);
        u16x4 o;
#pragma unroll
        for (int r = 0; r < 4; r++) o[r] = f2bf(eluP1(acc[t][u][r] + b4[r]));
        *(u16x4*)(phiq + (size_t)m_glb * DM + n_glb) = o;
      }
    }
  } else {
    u16* dst = (region == 1) ? phiKT : vT;
    const bool act = (region == 1);
#pragma unroll
    for (int t = 0; t < 4; t++) {
#pragma unroll
      for (int u = 0; u < 4; u++) {
        int n_row = tile_n * 128 + waveC * 64 + u * 16 + i16;   // 1024..3071
        int n_loc = n_row - region * 1024;                      // 0..1023
        int m_row = tile_m * 128 + waveR * 64 + t * 16 + q * 4;
        int bI = m_row >> 12, l = m_row & 4095;
        float bsc = biasQKV[n_row];
        u16x4 o;
#pragma unroll
        for (int r = 0; r < 4; r++) {
          float vv = acc[t][u][r] + bsc;
          if (act) vv = eluP1(vv);
          o[r] = f2bf(vv);
        }
        *(u16x4*)(dst + (size_t)bI * (DM * SL) + (size_t)n_loc * SL + l) = o;
      }
    }
  }
}

// ---------------- output GEMM: out = Vnew @ WO^T + bO (fp32) ----------------
__global__ __launch_bounds__(256) void gemm_out(const u16* __restrict__ A,
                                                const u16* __restrict__ W,
                                                const float* __restrict__ bias,
                                                float* __restrict__ outp) {
  const int K = 1024;
  const int bId = blockIdx.x;
  const int xcd = bId & 7, s = bId >> 3;        // s 0..127
  const int xm = xcd >> 1, xn = xcd & 1;
  const int tm_l = s >> 2, tn_l = s & 3;
  const int tile_m = xm * 32 + tm_l;            // 0..127
  const int tile_n = xn * 4 + tn_l;             // 0..7

  const int tid = threadIdx.x, lane = tid & 63, wv = tid >> 6;
  const int i16 = lane & 15, q = lane >> 4;
  const int waveR = wv >> 1, waveC = wv & 1;

  __shared__ u16 Xs[128 * 32];
  __shared__ u16 Ws[128 * 32];

  const int rbase = wv * 32 + (lane >> 2);
  const int kc = (lane & 3) ^ ((rbase >> 1) & 3);
  const u16* Ag = A + (size_t)(tile_m * 128 + rbase) * K + kc * 8;
  const u16* Wg = W + (size_t)(tile_n * 128 + rbase) * K + kc * 8;
  u16* XsB = Xs + wv * 1024;
  u16* WsB = Ws + wv * 1024;

  f32x4 acc[4][4] = {};

  for (int k0 = 0; k0 < K; k0 += 32) {
    __syncthreads();
    gll16(Ag + k0,          XsB);
    gll16(Ag + k0 + 16 * K, XsB + 512);
    gll16(Wg + k0,          WsB);
    gll16(Wg + k0 + 16 * K, WsB + 512);
    __syncthreads();

    short8 af[4], bfr[4];
#pragma unroll
    for (int t = 0; t < 4; t++) {
      int m = waveR * 64 + t * 16 + i16;
      af[t] = *(const short8*)(Ws + m * 32 + ((q ^ ((m >> 1) & 3)) << 3));
    }
#pragma unroll
    for (int u = 0; u < 4; u++) {
      int m = waveC * 64 + u * 16 + i16;
      bfr[u] = *(const short8*)(Xs + m * 32 + ((q ^ ((m >> 1) & 3)) << 3));
    }
#pragma unroll
    for (int t = 0; t < 4; t++)
#pragma unroll
      for (int u = 0; u < 4; u++)
        acc[t][u] = __builtin_amdgcn_mfma_f32_16x16x32_bf16(af[t], bfr[u], acc[t][u], 0, 0, 0);
  }

#pragma unroll
  for (int t = 0; t < 4; t++) {
#pragma unroll
    for (int u = 0; u < 4; u++) {
      int n_glb = tile_n * 128 + waveR * 64 + t * 16 + q * 4;
      int m_glb = tile_m * 128 + waveC * 64 + u * 16 + i16;
      f32x4 b4 = *(const f32x4*)(bias + n_glb);
      f32x4 o;
#pragma unroll
      for (int r = 0; r < 4; r++) o[r] = acc[t][u][r] + b4[r];
      *(f32x4*)(outp + (size_t)m_glb * DM + n_glb) = o;
    }
  }
}

// ---------------- KV partial + K_sum partial (fused) ----------------
// grid 256: block = (bh, chunk of L/4); 4 waves, each covers 256 l.
__global__ __launch_bounds__(256) void kv_partial(const u16* __restrict__ phiKT,
                                                  const u16* __restrict__ vT,
                                                  float* __restrict__ part,
                                                  float* __restrict__ ksumP) {
  int bh = blockIdx.x >> 2, chunk = blockIdx.x & 3;
  int tid = threadIdx.x, lane = tid & 63, wv = tid >> 6;
  int i16 = lane & 15, q = lane >> 4;
  const u16* Ab = phiKT + (size_t)bh * DK * SL;
  const u16* Bb = vT + (size_t)bh * DK * SL;
  int l0 = (chunk * 4 + wv) * 256;
  f32x4 acc[4][4] = {};
  float ks[4] = {};
  for (int kk = 0; kk < 256; kk += 32) {
    int col = l0 + kk + q * 8;
    short8 af[4], bfr[4];
#pragma unroll
    for (int t = 0; t < 4; t++) af[t] = *(const short8*)(Ab + (size_t)(t * 16 + i16) * SL + col);
#pragma unroll
    for (int u = 0; u < 4; u++) bfr[u] = *(const short8*)(Bb + (size_t)(u * 16 + i16) * SL + col);
#pragma unroll
    for (int t = 0; t < 4; t++)
#pragma unroll
      for (int j = 0; j < 8; j++) ks[t] += bf2f((u16)af[t][j]);
#pragma unroll
    for (int t = 0; t < 4; t++)
#pragma unroll
      for (int u = 0; u < 4; u++)
        acc[t][u] = __builtin_amdgcn_mfma_f32_16x16x32_bf16(af[t], bfr[u], acc[t][u], 0, 0, 0);
  }
  __shared__ float red[4][64][64];  // 64KB
  __shared__ float ksl[4][4][64];
#pragma unroll
  for (int t = 0; t < 4; t++)
#pragma unroll
    for (int u = 0; u < 4; u++)
#pragma unroll
      for (int r = 0; r < 4; r++)
        red[wv][t * 16 + q * 4 + r][u * 16 + i16] = acc[t][u][r];
#pragma unroll
  for (int t = 0; t < 4; t++) ksl[wv][q][t * 16 + i16] = ks[t];
  __syncthreads();
  int d = tid >> 2, mg = (tid & 3) * 16;
  for (int mm = 0; mm < 16; mm++) {
    int m = mg + mm;
    float s = red[0][d][m] + red[1][d][m] + red[2][d][m] + red[3][d][m];
    part[((size_t)(chunk * 64 + bh) * 64 + d) * 64 + m] = s;
  }
  if (tid < 64) {
    float s = 0.f;
#pragma unroll
    for (int w2 = 0; w2 < 4; w2++)
#pragma unroll
      for (int q2 = 0; q2 < 4; q2++) s += ksl[w2][q2][tid];
    ksumP[chunk * 4096 + bh * 64 + tid] = s;
  }
}

// ---------------- finalize: KVt (bf16, transposed [m][d]) + Ksum ----------------
__global__ __launch_bounds__(256) void kv_finalize(const float* __restrict__ part,
                                                   const float* __restrict__ ksumP,
                                                   u16* __restrict__ KVt,
                                                   float* __restrict__ Ksum) {
  int bh = blockIdx.x, tid = threadIdx.x;
  for (int e = tid; e < 4096; e += 256) {
    int d = e >> 6, m = e & 63;
    float s = part[((size_t)(0 * 64 + bh) * 64 + d) * 64 + m]
            + part[((size_t)(1 * 64 + bh) * 64 + d) * 64 + m]
            + part[((size_t)(2 * 64 + bh) * 64 + d) * 64 + m]
            + part[((size_t)(3 * 64 + bh) * 64 + d) * 64 + m];
    KVt[(size_t)bh * 4096 + m * 64 + d] = f2bf(s);
  }
  if (tid < 64) {
    float s = ksumP[0 * 4096 + bh * 64 + tid] + ksumP[1 * 4096 + bh * 64 + tid]
            + ksumP[2 * 4096 + bh * 64 + tid] + ksumP[3 * 4096 + bh * 64 + tid];
    Ksum[bh * 64 + tid] = s;
  }
}

// ---------------- V_new = (phi_q @ KV) * Z ----------------
__global__ __launch_bounds__(256) void vnew_kernel(const u16* __restrict__ phiq,
                                                   const u16* __restrict__ KVt,
                                                   const float* __restrict__ Ksum,
                                                   u16* __restrict__ Vnew) {
  int bh = blockIdx.x >> 5, lt = blockIdx.x & 31;
  int b = bh >> 4, h = bh & 15;
  int tid = threadIdx.x, lane = tid & 63, wv = tid >> 6;
  int i16 = lane & 15, q = lane >> 4;
  int waveM = wv & 1, waveL = wv >> 1;

  __shared__ float Zs[128];
  __shared__ float Pp[128][2];
  {
    int l = tid >> 1, half = tid & 1;
    const u16* pr = phiq + (size_t)(b * SL + lt * 128 + l) * DM + h * 64 + half * 32;
    float s = 0.f;
    for (int i = 0; i < 32; i += 8) {
      short8 v8 = *(const short8*)(pr + i);
#pragma unroll
      for (int j = 0; j < 8; j++) s += bf2f((u16)v8[j]) * Ksum[bh * 64 + half * 32 + i + j];
    }
    Pp[l][half] = s;
  }
  __syncthreads();
  if (tid < 128) Zs[tid] = 1.0f / (Pp[tid][0] + Pp[tid][1] + 1e-5f);
  __syncthreads();

  f32x4 acc[2][4] = {};
#pragma unroll
  for (int step = 0; step < 2; step++) {
    int d0 = step * 32 + q * 8;
    short8 af[2], bfr[4];
#pragma unroll
    for (int t = 0; t < 2; t++) {
      int m = waveM * 32 + t * 16 + i16;
      af[t] = *(const short8*)(KVt + (size_t)bh * 4096 + m * 64 + d0);
    }
#pragma unroll
    for (int u = 0; u < 4; u++) {
      int l = lt * 128 + waveL * 64 + u * 16 + i16;
      bfr[u] = *(const short8*)(phiq + (size_t)(b * SL + l) * DM + h * 64 + d0);
    }
#pragma unroll
    for (int t = 0; t < 2; t++)
#pragma unroll
      for (int u = 0; u < 4; u++)
        acc[t][u] = __builtin_amdgcn_mfma_f32_16x16x32_bf16(af[t], bfr[u], acc[t][u], 0, 0, 0);
  }

#pragma unroll
  for (int t = 0; t < 2; t++) {
#pragma unroll
    for (int u = 0; u < 4; u++) {
      int l_loc = waveL * 64 + u * 16 + i16;
      float z = Zs[l_loc];
      int n = h * 64 + waveM * 32 + t * 16 + q * 4;
      u16x4 o;
#pragma unroll
      for (int r = 0; r < 4; r++) o[r] = f2bf(acc[t][u][r] * z);
      *(u16x4*)(Vnew + (size_t)(b * SL + lt * 128 + l_loc) * DM + n) = o;
    }
  }
}

extern "C" void kernel_launch(void* const* d_in, const int* in_sizes, int n_in,
                              void* d_out, int out_size, void* d_ws, size_t ws_size,
                              hipStream_t stream) {
  const float* Qf = (const float*)d_in[0];
  const float* WQ = (const float*)d_in[1];
  const float* bQ = (const float*)d_in[2];
  const float* WK = (const float*)d_in[3];
  const float* bK = (const float*)d_in[4];
  const float* WV = (const float*)d_in[5];
  const float* bV = (const float*)d_in[6];
  const float* WO = (const float*)d_in[7];
  const float* bO = (const float*)d_in[8];

  const size_t MB = 1024ull * 1024ull;
  char* ws = (char*)d_ws;
  u16* Qbf     = (u16*)(ws + 0);          // 32MB; reused as Vnew
  u16* Vnew    = (u16*)(ws + 0);
  u16* Wqkv    = (u16*)(ws + 32 * MB);    // 6MB
  u16* Wobf    = (u16*)(ws + 38 * MB);    // 2MB
  float* biasQKV = (float*)(ws + 40 * MB);// 12KB
  u16* phiq    = (u16*)(ws + 41 * MB);    // 32MB
  u16* phiKT   = (u16*)(ws + 73 * MB);    // 32MB [b][h][d][l]
  u16* vT      = (u16*)(ws + 105 * MB);   // 32MB [b][h][m][l]
  u16* KVt     = (u16*)(ws + 137 * MB);   // 512KB [bh][m][d]
  float* Ksum  = (float*)(ws + 138 * MB); // 16KB
  float* part  = (float*)(ws + 139 * MB); // 4MB
  float* ksumP = (float*)(ws + 143 * MB); // 64KB

  // conversions
  cvt_f32_bf16<<<16384, 256, 0, stream>>>(Qf, Qbf, 4194304);
  cvt_w<<<4096, 256, 0, stream>>>(WQ, WK, WV, WO, Wqkv, Wobf);
  pack_bias<<<12, 256, 0, stream>>>(bQ, bK, bV, biasQKV);

  // fused QKV projection
  gemm_qkv<<<3072, 256, 0, stream>>>(Qbf, Wqkv, biasQKV, phiq, phiKT, vT);

  // KV + K_sum
  kv_partial<<<256, 256, 0, stream>>>(phiKT, vT, part, ksumP);
  kv_finalize<<<64, 256, 0, stream>>>(part, ksumP, KVt, Ksum);

  // V_new
  vnew_kernel<<<2048, 256, 0, stream>>>(phiq, KVt, Ksum, Vnew);

  // output projection (fp32 out)
  gemm_out<<<1024, 256, 0, stream>>>(Vnew, Wobf, bO, (float*)d_out);
}

// Round 3
// 372.406 us; speedup vs baseline: 1.1526x; 1.0299x over previous
//
#include <hip/hip_runtime.h>

typedef unsigned short u16;
typedef unsigned int   u32;
typedef __attribute__((ext_vector_type(8))) short short8;
typedef __attribute__((ext_vector_type(4))) float f32x4;
typedef __attribute__((ext_vector_type(4))) u16   u16x4;

#define NB 4
#define SL 4096
#define DM 1024
#define NH 16
#define DK 64

__device__ __forceinline__ u16 f2bf(float f) {
  u32 u = __builtin_bit_cast(u32, f);
  u = (u + 0x7fffu + ((u >> 16) & 1u)) >> 16;
  return (u16)u;
}
__device__ __forceinline__ float bf2f(u16 v) {
  u32 u = ((u32)v) << 16;
  return __builtin_bit_cast(float, u);
}
__device__ __forceinline__ float eluP1(float x) {
  return x > 0.f ? x + 1.f : __expf(x);
}
__device__ __forceinline__ void gll16(const u16* g, u16* l) {
  __builtin_amdgcn_global_load_lds((const __attribute__((address_space(1))) void*)g,
                                   (__attribute__((address_space(3))) void*)l, 16, 0, 0);
}

// ---------------- fp32 -> bf16 conversion (Q) ----------------
__global__ void cvt_f32_bf16(const float* __restrict__ in, u16* __restrict__ out, int n4) {
  int i = blockIdx.x * 256 + threadIdx.x;
  if (i < n4) {
    f32x4 f = *(const f32x4*)(in + (size_t)i * 4);
    u16x4 o = { f2bf(f[0]), f2bf(f[1]), f2bf(f[2]), f2bf(f[3]) };
    *(u16x4*)(out + (size_t)i * 4) = o;
  }
}

__global__ void cvt_w(const float* __restrict__ WQ, const float* __restrict__ WK,
                      const float* __restrict__ WV, const float* __restrict__ WO,
                      u16* __restrict__ Wqkv, u16* __restrict__ Wobf) {
  int r = blockIdx.x >> 10;
  int i = (blockIdx.x & 1023) * 256 + threadIdx.x;
  const float* src = r == 0 ? WQ : r == 1 ? WK : r == 2 ? WV : WO;
  u16* dst = (r == 3) ? Wobf : Wqkv + (size_t)r * 1048576;
  f32x4 f = *(const f32x4*)(src + (size_t)i * 4);
  u16x4 o = { f2bf(f[0]), f2bf(f[1]), f2bf(f[2]), f2bf(f[3]) };
  *(u16x4*)(dst + (size_t)i * 4) = o;
}

__global__ void pack_bias(const float* __restrict__ bQ, const float* __restrict__ bK,
                          const float* __restrict__ bV, float* __restrict__ biasQKV) {
  int i = blockIdx.x * 256 + threadIdx.x;  // 0..3071
  float v = (i < 1024) ? bQ[i] : (i < 2048) ? bK[i - 1024] : bV[i - 2048];
  biasQKV[i] = v;
}

// ---------------- fused QKV GEMM, dbuf K-loop, LDS-transpose epilogue ----------------
// A: Qbf [16384][1024]. Wqkv: [3072][1024].
// region 0 (Q): store phi_q [b*l][n] bf16, elu+1
// region 1 (K): store phiKT [b][n][l] bf16, elu+1
// region 2 (V): store vT   [b][n][l] bf16, no act
__global__ __launch_bounds__(256) void gemm_qkv(const u16* __restrict__ A,
                                                const u16* __restrict__ Wqkv,
                                                const float* __restrict__ biasQKV,
                                                u16* __restrict__ phiq,
                                                u16* __restrict__ phiKT,
                                                u16* __restrict__ vT) {
  const int K = 1024;
  // XCD band: each xcd owns tile_m in [xcd*16, xcd*16+16), tn-outer tm-inner
  const int bId = blockIdx.x;
  const int xcd = bId & 7, s = bId >> 3;        // s 0..383
  const int tile_n = s >> 4;                    // 0..23
  const int tile_m = xcd * 16 + (s & 15);       // 0..127
  const int region = tile_n >> 3;               // 0=Q,1=K,2=V

  const int tid = threadIdx.x, lane = tid & 63, wv = tid >> 6;
  const int i16 = lane & 15, q = lane >> 4;
  const int waveR = wv >> 1, waveC = wv & 1;

  __shared__ u16 smem[17408];  // staging: 2 x (X 4096 | W 4096); epilogue: T[128][136]

  const int rbase = wv * 32 + (lane >> 2);
  const int kc = (lane & 3) ^ ((rbase >> 1) & 3);
  const u16* Ag = A + (size_t)(tile_m * 128 + rbase) * K + kc * 8;
  const u16* Wg = Wqkv + (size_t)(tile_n * 128 + rbase) * K + kc * 8;

  f32x4 acc[4][4] = {};

  // prologue stage k0=0 into buf0
  {
    u16* XsB = smem + wv * 1024;
    u16* WsB = smem + 4096 + wv * 1024;
    gll16(Ag, XsB);
    gll16(Ag + 16 * K, XsB + 512);
    gll16(Wg, WsB);
    gll16(Wg + 16 * K, WsB + 512);
  }

  for (int k = 0; k < 32; k++) {
    const int cur = k & 1;
    __syncthreads();  // drains stage(k) for all waves; compute(k-1) done
    if (k < 31) {
      const int nxt = cur ^ 1;
      const int k0 = (k + 1) * 32;
      u16* XsB = smem + nxt * 8192 + wv * 1024;
      u16* WsB = smem + nxt * 8192 + 4096 + wv * 1024;
      gll16(Ag + k0,          XsB);
      gll16(Ag + k0 + 16 * K, XsB + 512);
      gll16(Wg + k0,          WsB);
      gll16(Wg + k0 + 16 * K, WsB + 512);
    }
    const u16* Xc = smem + cur * 8192;
    const u16* Wc = Xc + 4096;
    const u16* aT = (region == 0) ? Wc : Xc;
    const u16* bT = (region == 0) ? Xc : Wc;

    short8 af[4], bfr[4];
#pragma unroll
    for (int t = 0; t < 4; t++) {
      int m = waveR * 64 + t * 16 + i16;
      af[t] = *(const short8*)(aT + m * 32 + ((q ^ ((m >> 1) & 3)) << 3));
    }
#pragma unroll
    for (int u = 0; u < 4; u++) {
      int m = waveC * 64 + u * 16 + i16;
      bfr[u] = *(const short8*)(bT + m * 32 + ((q ^ ((m >> 1) & 3)) << 3));
    }
#pragma unroll
    for (int t = 0; t < 4; t++)
#pragma unroll
      for (int u = 0; u < 4; u++)
        acc[t][u] = __builtin_amdgcn_mfma_f32_16x16x32_bf16(af[t], bfr[u], acc[t][u], 0, 0, 0);
  }

  // ---- epilogue: transpose via LDS T[128][136], then coalesced stores ----
  // T[cI][rI]: cI = i16-dim (B-rows), rI = reg-dim (A-rows)
  __syncthreads();  // everyone done reading staging LDS
  u16* T = smem;
#pragma unroll
  for (int t = 0; t < 4; t++) {
#pragma unroll
    for (int u = 0; u < 4; u++) {
      int cI = waveC * 64 + u * 16 + i16;
      int rI = waveR * 64 + t * 16 + q * 4;
      u16x4 o;
      if (region == 0) {
        f32x4 b4 = *(const f32x4*)(biasQKV + tile_n * 128 + rI);
#pragma unroll
        for (int r = 0; r < 4; r++) o[r] = f2bf(eluP1(acc[t][u][r] + b4[r]));
      } else {
        float bs = biasQKV[tile_n * 128 + cI];
#pragma unroll
        for (int r = 0; r < 4; r++) {
          float vv = acc[t][u][r] + bs;
          if (region == 1) vv = eluP1(vv);
          o[r] = f2bf(vv);
        }
      }
      *(u16x4*)(T + cI * 136 + rI) = o;
    }
  }
  __syncthreads();
  {
    const int Rl = tid >> 4, j = tid & 15;
    u16* dst = (region == 1) ? phiKT : vT;
#pragma unroll
    for (int p = 0; p < 8; p++) {
      int R = p * 16 + Rl;
      short8 v8 = *(const short8*)(T + R * 136 + j * 8);
      if (region == 0) {
        // row R = l-dim (tile_m), col = n-dim (tile_n)
        *(short8*)(phiq + (size_t)(tile_m * 128 + R) * DM + tile_n * 128 + j * 8) = v8;
      } else {
        // row R = n-dim (tile_n), col = l-dim (tile_m)
        int n_loc = tile_n * 128 + R - region * 1024;
        int bI = tile_m >> 5;
        int l = (tile_m & 31) * 128 + j * 8;
        *(short8*)(dst + ((size_t)bI * 1024 + n_loc) * 4096 + l) = v8;
      }
    }
  }
}

// ---------------- output GEMM: out = Vnew @ WO^T + bO (fp32), dbuf + LDS transpose ----------------
__global__ __launch_bounds__(256) void gemm_out(const u16* __restrict__ A,
                                                const u16* __restrict__ W,
                                                const float* __restrict__ bias,
                                                float* __restrict__ outp) {
  const int K = 1024;
  const int bId = blockIdx.x;
  const int xcd = bId & 7, s = bId >> 3;        // s 0..127
  const int tile_n = s >> 4;                    // 0..7
  const int tile_m = xcd * 16 + (s & 15);       // 0..127

  const int tid = threadIdx.x, lane = tid & 63, wv = tid >> 6;
  const int i16 = lane & 15, q = lane >> 4;
  const int waveR = wv >> 1, waveC = wv & 1;

  __shared__ u16 smem[17408];

  const int rbase = wv * 32 + (lane >> 2);
  const int kc = (lane & 3) ^ ((rbase >> 1) & 3);
  const u16* Ag = A + (size_t)(tile_m * 128 + rbase) * K + kc * 8;
  const u16* Wg = W + (size_t)(tile_n * 128 + rbase) * K + kc * 8;

  f32x4 acc[4][4] = {};

  {
    u16* XsB = smem + wv * 1024;
    u16* WsB = smem + 4096 + wv * 1024;
    gll16(Ag, XsB);
    gll16(Ag + 16 * K, XsB + 512);
    gll16(Wg, WsB);
    gll16(Wg + 16 * K, WsB + 512);
  }

  for (int k = 0; k < 32; k++) {
    const int cur = k & 1;
    __syncthreads();
    if (k < 31) {
      const int nxt = cur ^ 1;
      const int k0 = (k + 1) * 32;
      u16* XsB = smem + nxt * 8192 + wv * 1024;
      u16* WsB = smem + nxt * 8192 + 4096 + wv * 1024;
      gll16(Ag + k0,          XsB);
      gll16(Ag + k0 + 16 * K, XsB + 512);
      gll16(Wg + k0,          WsB);
      gll16(Wg + k0 + 16 * K, WsB + 512);
    }
    const u16* Xc = smem + cur * 8192;
    const u16* Wc = Xc + 4096;

    short8 af[4], bfr[4];
#pragma unroll
    for (int t = 0; t < 4; t++) {
      int m = waveR * 64 + t * 16 + i16;
      af[t] = *(const short8*)(Wc + m * 32 + ((q ^ ((m >> 1) & 3)) << 3));
    }
#pragma unroll
    for (int u = 0; u < 4; u++) {
      int m = waveC * 64 + u * 16 + i16;
      bfr[u] = *(const short8*)(Xc + m * 32 + ((q ^ ((m >> 1) & 3)) << 3));
    }
#pragma unroll
    for (int t = 0; t < 4; t++)
#pragma unroll
      for (int u = 0; u < 4; u++)
        acc[t][u] = __builtin_amdgcn_mfma_f32_16x16x32_bf16(af[t], bfr[u], acc[t][u], 0, 0, 0);
  }

  // epilogue: fp32 transpose in two n-halves. Tf[l 128][n 68pad]
  float* Tf = (float*)smem;  // 128*68*4 = 34816 B
#pragma unroll
  for (int half = 0; half < 2; half++) {
    __syncthreads();
    if (waveR == half) {
#pragma unroll
      for (int t = 0; t < 4; t++) {
#pragma unroll
        for (int u = 0; u < 4; u++) {
          int cI = waveC * 64 + u * 16 + i16;      // l-dim
          int rIh = t * 16 + q * 4;                // n within half
          f32x4 b4 = *(const f32x4*)(bias + tile_n * 128 + half * 64 + rIh);
          f32x4 o;
#pragma unroll
          for (int r = 0; r < 4; r++) o[r] = acc[t][u][r] + b4[r];
          *(f32x4*)(Tf + cI * 68 + rIh) = o;
        }
      }
    }
    __syncthreads();
    const int Rl = tid >> 4, j = tid & 15;
#pragma unroll
    for (int p = 0; p < 8; p++) {
      int R = p * 16 + Rl;
      f32x4 v = *(const f32x4*)(Tf + R * 68 + j * 4);
      *(f32x4*)(outp + (size_t)(tile_m * 128 + R) * DM + tile_n * 128 + half * 64 + j * 4) = v;
    }
  }
}

// ---------------- KV partial + K_sum partial (fused) ----------------
__global__ __launch_bounds__(256) void kv_partial(const u16* __restrict__ phiKT,
                                                  const u16* __restrict__ vT,
                                                  float* __restrict__ part,
                                                  float* __restrict__ ksumP) {
  int bh = blockIdx.x >> 2, chunk = blockIdx.x & 3;
  int tid = threadIdx.x, lane = tid & 63, wv = tid >> 6;
  int i16 = lane & 15, q = lane >> 4;
  const u16* Ab = phiKT + (size_t)bh * DK * SL;
  const u16* Bb = vT + (size_t)bh * DK * SL;
  int l0 = (chunk * 4 + wv) * 256;
  f32x4 acc[4][4] = {};
  float ks[4] = {};
  for (int kk = 0; kk < 256; kk += 32) {
    int col = l0 + kk + q * 8;
    short8 af[4], bfr[4];
#pragma unroll
    for (int t = 0; t < 4; t++) af[t] = *(const short8*)(Ab + (size_t)(t * 16 + i16) * SL + col);
#pragma unroll
    for (int u = 0; u < 4; u++) bfr[u] = *(const short8*)(Bb + (size_t)(u * 16 + i16) * SL + col);
#pragma unroll
    for (int t = 0; t < 4; t++)
#pragma unroll
      for (int j = 0; j < 8; j++) ks[t] += bf2f((u16)af[t][j]);
#pragma unroll
    for (int t = 0; t < 4; t++)
#pragma unroll
      for (int u = 0; u < 4; u++)
        acc[t][u] = __builtin_amdgcn_mfma_f32_16x16x32_bf16(af[t], bfr[u], acc[t][u], 0, 0, 0);
  }
  __shared__ float red[4][64][64];  // 64KB
  __shared__ float ksl[4][4][64];
#pragma unroll
  for (int t = 0; t < 4; t++)
#pragma unroll
    for (int u = 0; u < 4; u++)
#pragma unroll
      for (int r = 0; r < 4; r++)
        red[wv][t * 16 + q * 4 + r][u * 16 + i16] = acc[t][u][r];
#pragma unroll
  for (int t = 0; t < 4; t++) ksl[wv][q][t * 16 + i16] = ks[t];
  __syncthreads();
  int d = tid >> 2, mg = (tid & 3) * 16;
#pragma unroll
  for (int c = 0; c < 4; c++) {
    int m = mg + c * 4;
    f32x4 o;
#pragma unroll
    for (int r = 0; r < 4; r++)
      o[r] = red[0][d][m + r] + red[1][d][m + r] + red[2][d][m + r] + red[3][d][m + r];
    *(f32x4*)(part + ((size_t)(chunk * 64 + bh) * 64 + d) * 64 + m) = o;
  }
  if (tid < 64) {
    float s = 0.f;
#pragma unroll
    for (int w2 = 0; w2 < 4; w2++)
#pragma unroll
      for (int q2 = 0; q2 < 4; q2++) s += ksl[w2][q2][tid];
    ksumP[chunk * 4096 + bh * 64 + tid] = s;
  }
}

// ---------------- finalize: KVt (bf16, [bh][m][d]) + Ksum ----------------
__global__ __launch_bounds__(256) void kv_finalize(const float* __restrict__ part,
                                                   const float* __restrict__ ksumP,
                                                   u16* __restrict__ KVt,
                                                   float* __restrict__ Ksum) {
  int bh = blockIdx.x, tid = threadIdx.x;
  for (int e = tid; e < 4096; e += 256) {
    int d = e >> 6, m = e & 63;
    float s = part[((size_t)(0 * 64 + bh) * 64 + d) * 64 + m]
            + part[((size_t)(1 * 64 + bh) * 64 + d) * 64 + m]
            + part[((size_t)(2 * 64 + bh) * 64 + d) * 64 + m]
            + part[((size_t)(3 * 64 + bh) * 64 + d) * 64 + m];
    KVt[(size_t)bh * 4096 + m * 64 + d] = f2bf(s);
  }
  if (tid < 64) {
    float s = ksumP[0 * 4096 + bh * 64 + tid] + ksumP[1 * 4096 + bh * 64 + tid]
            + ksumP[2 * 4096 + bh * 64 + tid] + ksumP[3 * 4096 + bh * 64 + tid];
    Ksum[bh * 64 + tid] = s;
  }
}

// ---------------- V_new = (phi_q @ KV) * Z, LDS-transpose store ----------------
__global__ __launch_bounds__(256) void vnew_kernel(const u16* __restrict__ phiq,
                                                   const u16* __restrict__ KVt,
                                                   const float* __restrict__ Ksum,
                                                   u16* __restrict__ Vnew) {
  int bh = blockIdx.x >> 5, lt = blockIdx.x & 31;
  int b = bh >> 4, h = bh & 15;
  int tid = threadIdx.x, lane = tid & 63, wv = tid >> 6;
  int i16 = lane & 15, q = lane >> 4;
  int waveM = wv & 1, waveL = wv >> 1;

  __shared__ float Zs[128];
  __shared__ float Pp[128][2];
  __shared__ u16 T[128 * 72];  // 18432 B
  {
    int l = tid >> 1, half = tid & 1;
    const u16* pr = phiq + (size_t)(b * SL + lt * 128 + l) * DM + h * 64 + half * 32;
    float s = 0.f;
    for (int i = 0; i < 32; i += 8) {
      short8 v8 = *(const short8*)(pr + i);
#pragma unroll
      for (int j = 0; j < 8; j++) s += bf2f((u16)v8[j]) * Ksum[bh * 64 + half * 32 + i + j];
    }
    Pp[l][half] = s;
  }
  __syncthreads();
  if (tid < 128) Zs[tid] = 1.0f / (Pp[tid][0] + Pp[tid][1] + 1e-5f);
  __syncthreads();

  f32x4 acc[2][4] = {};
#pragma unroll
  for (int step = 0; step < 2; step++) {
    int d0 = step * 32 + q * 8;
    short8 af[2], bfr[4];
#pragma unroll
    for (int t = 0; t < 2; t++) {
      int m = waveM * 32 + t * 16 + i16;
      af[t] = *(const short8*)(KVt + (size_t)bh * 4096 + m * 64 + d0);
    }
#pragma unroll
    for (int u = 0; u < 4; u++) {
      int l = lt * 128 + waveL * 64 + u * 16 + i16;
      bfr[u] = *(const short8*)(phiq + (size_t)(b * SL + l) * DM + h * 64 + d0);
    }
#pragma unroll
    for (int t = 0; t < 2; t++)
#pragma unroll
      for (int u = 0; u < 4; u++)
        acc[t][u] = __builtin_amdgcn_mfma_f32_16x16x32_bf16(af[t], bfr[u], acc[t][u], 0, 0, 0);
  }

  // write T[l 128][n 72pad], n-local range 64
#pragma unroll
  for (int t = 0; t < 2; t++) {
#pragma unroll
    for (int u = 0; u < 4; u++) {
      int cI = waveL * 64 + u * 16 + i16;           // l
      int nI = waveM * 32 + t * 16 + q * 4;         // n local
      float z = Zs[cI];
      u16x4 o;
#pragma unroll
      for (int r = 0; r < 4; r++) o[r] = f2bf(acc[t][u][r] * z);
      *(u16x4*)(T + cI * 72 + nI) = o;
    }
  }
  __syncthreads();
  {
    const int Rl = tid >> 3, j = tid & 7;
#pragma unroll
    for (int p = 0; p < 4; p++) {
      int R = p * 32 + Rl;
      short8 v8 = *(const short8*)(T + R * 72 + j * 8);
      *(short8*)(Vnew + (size_t)(b * SL + lt * 128 + R) * DM + h * 64 + j * 8) = v8;
    }
  }
}

extern "C" void kernel_launch(void* const* d_in, const int* in_sizes, int n_in,
                              void* d_out, int out_size, void* d_ws, size_t ws_size,
                              hipStream_t stream) {
  const float* Qf = (const float*)d_in[0];
  const float* WQ = (const float*)d_in[1];
  const float* bQ = (const float*)d_in[2];
  const float* WK = (const float*)d_in[3];
  const float* bK = (const float*)d_in[4];
  const float* WV = (const float*)d_in[5];
  const float* bV = (const float*)d_in[6];
  const float* WO = (const float*)d_in[7];
  const float* bO = (const float*)d_in[8];

  const size_t MB = 1024ull * 1024ull;
  char* ws = (char*)d_ws;
  u16* Qbf     = (u16*)(ws + 0);          // 32MB; reused as Vnew
  u16* Vnew    = (u16*)(ws + 0);
  u16* Wqkv    = (u16*)(ws + 32 * MB);    // 6MB
  u16* Wobf    = (u16*)(ws + 38 * MB);    // 2MB
  float* biasQKV = (float*)(ws + 40 * MB);// 12KB
  u16* phiq    = (u16*)(ws + 41 * MB);    // 32MB
  u16* phiKT   = (u16*)(ws + 73 * MB);    // 32MB [b][h][d][l]
  u16* vT      = (u16*)(ws + 105 * MB);   // 32MB [b][h][m][l]
  u16* KVt     = (u16*)(ws + 137 * MB);   // 512KB [bh][m][d]
  float* Ksum  = (float*)(ws + 138 * MB); // 16KB
  float* part  = (float*)(ws + 139 * MB); // 4MB
  float* ksumP = (float*)(ws + 143 * MB); // 64KB

  cvt_f32_bf16<<<16384, 256, 0, stream>>>(Qf, Qbf, 4194304);
  cvt_w<<<4096, 256, 0, stream>>>(WQ, WK, WV, WO, Wqkv, Wobf);
  pack_bias<<<12, 256, 0, stream>>>(bQ, bK, bV, biasQKV);

  gemm_qkv<<<3072, 256, 0, stream>>>(Qbf, Wqkv, biasQKV, phiq, phiKT, vT);

  kv_partial<<<256, 256, 0, stream>>>(phiKT, vT, part, ksumP);
  kv_finalize<<<64, 256, 0, stream>>>(part, ksumP, KVt, Ksum);

  vnew_kernel<<<2048, 256, 0, stream>>>(phiq, KVt, Ksum, Vnew);

  gemm_out<<<1024, 256, 0, stream>>>(Vnew, Wobf, bO, (float*)d_out);
}

// Round 5
// 361.446 us; speedup vs baseline: 1.1875x; 1.0303x over previous
//
#include <hip/hip_runtime.h>

typedef unsigned short u16;
typedef unsigned int   u32;
typedef __attribute__((ext_vector_type(8))) short short8;
typedef __attribute__((ext_vector_type(4))) float f32x4;
typedef __attribute__((ext_vector_type(4))) u16   u16x4;

#define NB 4
#define SL 4096
#define DM 1024
#define NH 16
#define DK 64

__device__ __forceinline__ u16 f2bf(float f) {
  u32 u = __builtin_bit_cast(u32, f);
  u = (u + 0x7fffu + ((u >> 16) & 1u)) >> 16;
  return (u16)u;
}
__device__ __forceinline__ float bf2f(u16 v) {
  u32 u = ((u32)v) << 16;
  return __builtin_bit_cast(float, u);
}
__device__ __forceinline__ float eluP1(float x) {
  return x > 0.f ? x + 1.f : __expf(x);
}
// NOTE: the imm offset of global_load_lds applies to BOTH global and LDS
// addresses (LLVM intrinsic semantics) — always pass 0 and do pointer math.
#define GLL(gp, lp) __builtin_amdgcn_global_load_lds(     \
    (const __attribute__((address_space(1))) void*)(gp),  \
    (__attribute__((address_space(3))) void*)(lp), 16, 0, 0)

// ---------------- merged conversions ----------------
__global__ void cvt_all(const float* __restrict__ Qf,
                        const float* __restrict__ WQ, const float* __restrict__ WK,
                        const float* __restrict__ WV, const float* __restrict__ WO,
                        const float* __restrict__ bQ, const float* __restrict__ bK,
                        const float* __restrict__ bV,
                        u16* __restrict__ Qbf, u16* __restrict__ Wqkv,
                        u16* __restrict__ Wobf, float* __restrict__ biasQKV) {
  int b = blockIdx.x, tid = threadIdx.x;
  if (b < 16384) {
    int i = b * 256 + tid;
    f32x4 f = *(const f32x4*)(Qf + (size_t)i * 4);
    u16x4 o = { f2bf(f[0]), f2bf(f[1]), f2bf(f[2]), f2bf(f[3]) };
    *(u16x4*)(Qbf + (size_t)i * 4) = o;
  } else if (b < 20480) {
    int r = (b - 16384) >> 10;
    int i = ((b - 16384) & 1023) * 256 + tid;
    const float* src = r == 0 ? WQ : r == 1 ? WK : r == 2 ? WV : WO;
    u16* dst = (r == 3) ? Wobf : Wqkv + (size_t)r * 1048576;
    f32x4 f = *(const f32x4*)(src + (size_t)i * 4);
    u16x4 o = { f2bf(f[0]), f2bf(f[1]), f2bf(f[2]), f2bf(f[3]) };
    *(u16x4*)(dst + (size_t)i * 4) = o;
  } else {
    int i = (b - 20480) * 256 + tid;
    if (i < 3072) {
      float v = (i < 1024) ? bQ[i] : (i < 2048) ? bK[i - 1024] : bV[i - 2048];
      biasQKV[i] = v;
    }
  }
}

// compute one K-step from buffer at element offset CB (0 or 8192)
#define COMPUTE(CB)                                                          \
  do {                                                                       \
    short8 af_[4], bf_[4];                                                   \
    _Pragma("unroll") for (int t = 0; t < 4; t++)                            \
        af_[t] = *(const short8*)(aP[t] + (CB));                             \
    _Pragma("unroll") for (int u = 0; u < 4; u++)                            \
        bf_[u] = *(const short8*)(bP[u] + (CB));                             \
    _Pragma("unroll") for (int t = 0; t < 4; t++)                            \
      _Pragma("unroll") for (int u = 0; u < 4; u++)                          \
          acc[t][u] = __builtin_amdgcn_mfma_f32_16x16x32_bf16(               \
              af_[t], bf_[u], acc[t][u], 0, 0, 0);                           \
  } while (0)

#define STAGE4(XB, WB)                                        \
  do {                                                        \
    GLL(Ag0, XB); GLL(Ag1, (XB) + 512);                       \
    GLL(Wg0, WB); GLL(Wg1, (WB) + 512);                       \
    Ag0 += 32; Ag1 += 32; Wg0 += 32; Wg1 += 32;               \
  } while (0)

// ---------------- fused QKV GEMM: static-address dbuf K-loop ----------------
// region 0 (Q): store phi_q [b*l][n] bf16, elu+1
// region 1 (K): store phiKT [b][n][l] bf16, elu+1
// region 2 (V): store vT   [b][n][l] bf16, no act
__global__ __launch_bounds__(256) void gemm_qkv(const u16* __restrict__ A,
                                                const u16* __restrict__ Wqkv,
                                                const float* __restrict__ biasQKV,
                                                u16* __restrict__ phiq,
                                                u16* __restrict__ phiKT,
                                                u16* __restrict__ vT) {
  const int K = 1024;
  // rectangle swizzle: 32 tile_m x 12 tile_n per XCD
  const int bId = blockIdx.x;
  const int xcd = bId & 7, s = bId >> 3;        // s 0..383
  const int xm = xcd >> 1, xn = xcd & 1;
  const int tm_l = s / 12, tn_l = s - tm_l * 12;
  const int tile_m = xm * 32 + tm_l;            // 0..127
  const int tile_n = xn * 12 + tn_l;            // 0..23
  const int region = tile_n >> 3;               // 0=Q,1=K,2=V

  const int tid = threadIdx.x, lane = tid & 63, wv = tid >> 6;
  const int i16 = lane & 15, q = lane >> 4;
  const int waveR = wv >> 1, waveC = wv & 1;

  __shared__ u16 smem[16384];  // buf0: X[0,4096) W[4096,8192); buf1: +8192

  const int rbase = wv * 32 + (lane >> 2);
  const int kc = (lane & 3) ^ ((rbase >> 1) & 3);
  const u16* Ag0 = A + (size_t)(tile_m * 128 + rbase) * K + kc * 8;
  const u16* Ag1 = Ag0 + 16 * K;
  const u16* Wg0 = Wqkv + (size_t)(tile_n * 128 + rbase) * K + kc * 8;
  const u16* Wg1 = Wg0 + 16 * K;
  u16* X0 = smem + wv * 1024;
  u16* W0 = smem + 4096 + wv * 1024;
  u16* X1 = X0 + 8192;
  u16* W1 = W0 + 8192;

  // loop-invariant fragment pointers (buf0 base)
  const u16* aT0 = (region == 0) ? smem + 4096 : smem;
  const u16* bT0 = (region == 0) ? smem : smem + 4096;
  const u16* aP[4];
  const u16* bP[4];
#pragma unroll
  for (int t = 0; t < 4; t++) {
    int m = waveR * 64 + t * 16 + i16;
    aP[t] = aT0 + m * 32 + ((q ^ ((m >> 1) & 3)) << 3);
  }
#pragma unroll
  for (int u = 0; u < 4; u++) {
    int m = waveC * 64 + u * 16 + i16;
    bP[u] = bT0 + m * 32 + ((q ^ ((m >> 1) & 3)) << 3);
  }

  f32x4 acc[4][4] = {};

  // prologue: stage k-step 0 into buf0
  STAGE4(X0, W0);

  for (int kk = 0; kk < 16; kk++) {
    __syncthreads();                 // stage(2kk) complete
    STAGE4(X1, W1);                  // stage 2kk+1 -> buf1
    COMPUTE(0);                      // compute 2kk (buf0)
    __syncthreads();                 // stage(2kk+1) complete, buf0 free
    if (kk < 15) STAGE4(X0, W0);     // stage 2kk+2 -> buf0
    COMPUTE(8192);                   // compute 2kk+1 (buf1)
  }

  // ---- epilogue: 2-phase transpose via LDS T[128][72] u16 ----
  u16* T = smem;
  u16* dstT = (region == 1) ? phiKT : vT;
#pragma unroll
  for (int h = 0; h < 2; h++) {
    __syncthreads();
    if (waveR == h) {
#pragma unroll
      for (int t = 0; t < 4; t++) {
#pragma unroll
        for (int u = 0; u < 4; u++) {
          int cI = waveC * 64 + u * 16 + i16;
          int rI = t * 16 + q * 4;
          u16x4 o;
          if (region == 0) {
            f32x4 b4 = *(const f32x4*)(biasQKV + tile_n * 128 + h * 64 + rI);
#pragma unroll
            for (int r = 0; r < 4; r++) o[r] = f2bf(eluP1(acc[t][u][r] + b4[r]));
          } else {
            float bs = biasQKV[tile_n * 128 + cI];
#pragma unroll
            for (int r = 0; r < 4; r++) {
              float vv = acc[t][u][r] + bs;
              if (region == 1) vv = eluP1(vv);
              o[r] = f2bf(vv);
            }
          }
          *(u16x4*)(T + cI * 72 + rI) = o;
        }
      }
    }
    __syncthreads();
    const int Rl = tid >> 3, j = tid & 7;
#pragma unroll
    for (int p = 0; p < 4; p++) {
      int R = p * 32 + Rl;
      short8 v8 = *(const short8*)(T + R * 72 + j * 8);
      if (region == 0) {
        *(short8*)(phiq + (size_t)(tile_m * 128 + R) * DM + tile_n * 128 + h * 64 + j * 8) = v8;
      } else {
        int n_loc = tile_n * 128 + R - region * 1024;
        int bI = tile_m >> 5;
        int l = (tile_m & 31) * 128 + h * 64 + j * 8;
        *(short8*)(dstT + ((size_t)bI * 1024 + n_loc) * 4096 + l) = v8;
      }
    }
  }
}

// ---------------- output GEMM: out = Vnew @ WO^T + bO (fp32) ----------------
__global__ __launch_bounds__(256) void gemm_out(const u16* __restrict__ A,
                                                const u16* __restrict__ W,
                                                const float* __restrict__ bias,
                                                float* __restrict__ outp) {
  const int K = 1024;
  const int bId = blockIdx.x;
  const int xcd = bId & 7, s = bId >> 3;        // s 0..127
  const int xm = xcd >> 1, xn = xcd & 1;
  const int tm_l = s >> 2, tn_l = s & 3;
  const int tile_m = xm * 32 + tm_l;            // 0..127
  const int tile_n = xn * 4 + tn_l;             // 0..7

  const int tid = threadIdx.x, lane = tid & 63, wv = tid >> 6;
  const int i16 = lane & 15, q = lane >> 4;
  const int waveR = wv >> 1, waveC = wv & 1;

  __shared__ u16 smem[17408];  // staging 32KB; epilogue Tf[128][68] f32 = 34816B

  const int rbase = wv * 32 + (lane >> 2);
  const int kc = (lane & 3) ^ ((rbase >> 1) & 3);
  const u16* Ag0 = A + (size_t)(tile_m * 128 + rbase) * K + kc * 8;
  const u16* Ag1 = Ag0 + 16 * K;
  const u16* Wg0 = W + (size_t)(tile_n * 128 + rbase) * K + kc * 8;
  const u16* Wg1 = Wg0 + 16 * K;
  u16* X0 = smem + wv * 1024;
  u16* W0 = smem + 4096 + wv * 1024;
  u16* X1 = X0 + 8192;
  u16* W1 = W0 + 8192;

  // A-op = W rows (D rows = n), B-op = X rows (cols = l)
  const u16* aP[4];
  const u16* bP[4];
#pragma unroll
  for (int t = 0; t < 4; t++) {
    int m = waveR * 64 + t * 16 + i16;
    aP[t] = smem + 4096 + m * 32 + ((q ^ ((m >> 1) & 3)) << 3);
  }
#pragma unroll
  for (int u = 0; u < 4; u++) {
    int m = waveC * 64 + u * 16 + i16;
    bP[u] = smem + m * 32 + ((q ^ ((m >> 1) & 3)) << 3);
  }

  f32x4 acc[4][4] = {};

  STAGE4(X0, W0);

  for (int kk = 0; kk < 16; kk++) {
    __syncthreads();
    STAGE4(X1, W1);
    COMPUTE(0);
    __syncthreads();
    if (kk < 15) STAGE4(X0, W0);
    COMPUTE(8192);
  }

  // epilogue: fp32 transpose, two n-halves. Tf[l 128][n 68pad]
  float* Tf = (float*)smem;
#pragma unroll
  for (int half = 0; half < 2; half++) {
    __syncthreads();
    if (waveR == half) {
#pragma unroll
      for (int t = 0; t < 4; t++) {
#pragma unroll
        for (int u = 0; u < 4; u++) {
          int cI = waveC * 64 + u * 16 + i16;      // l-dim
          int rIh = t * 16 + q * 4;                // n within half
          f32x4 b4 = *(const f32x4*)(bias + tile_n * 128 + half * 64 + rIh);
          f32x4 o;
#pragma unroll
          for (int r = 0; r < 4; r++) o[r] = acc[t][u][r] + b4[r];
          *(f32x4*)(Tf + cI * 68 + rIh) = o;
        }
      }
    }
    __syncthreads();
    const int Rl = tid >> 4, j = tid & 15;
#pragma unroll
    for (int p = 0; p < 8; p++) {
      int R = p * 16 + Rl;
      f32x4 v = *(const f32x4*)(Tf + R * 68 + j * 4);
      *(f32x4*)(outp + (size_t)(tile_m * 128 + R) * DM + tile_n * 128 + half * 64 + j * 4) = v;
    }
  }
}

// ---------------- KV partial + K_sum partial (fused) ----------------
__global__ __launch_bounds__(256) void kv_partial(const u16* __restrict__ phiKT,
                                                  const u16* __restrict__ vT,
                                                  float* __restrict__ part,
                                                  float* __restrict__ ksumP) {
  int bh = blockIdx.x >> 2, chunk = blockIdx.x & 3;
  int tid = threadIdx.x, lane = tid & 63, wv = tid >> 6;
  int i16 = lane & 15, q = lane >> 4;
  const u16* Ab = phiKT + (size_t)bh * DK * SL;
  const u16* Bb = vT + (size_t)bh * DK * SL;
  int l0 = (chunk * 4 + wv) * 256;
  f32x4 acc[4][4] = {};
  float ks[4] = {};
  for (int kk = 0; kk < 256; kk += 32) {
    int col = l0 + kk + q * 8;
    short8 af[4], bfr[4];
#pragma unroll
    for (int t = 0; t < 4; t++) af[t] = *(const short8*)(Ab + (size_t)(t * 16 + i16) * SL + col);
#pragma unroll
    for (int u = 0; u < 4; u++) bfr[u] = *(const short8*)(Bb + (size_t)(u * 16 + i16) * SL + col);
#pragma unroll
    for (int t = 0; t < 4; t++)
#pragma unroll
      for (int j = 0; j < 8; j++) ks[t] += bf2f((u16)af[t][j]);
#pragma unroll
    for (int t = 0; t < 4; t++)
#pragma unroll
      for (int u = 0; u < 4; u++)
        acc[t][u] = __builtin_amdgcn_mfma_f32_16x16x32_bf16(af[t], bfr[u], acc[t][u], 0, 0, 0);
  }
  __shared__ float red[4][64][64];  // 64KB
  __shared__ float ksl[4][4][64];
#pragma unroll
  for (int t = 0; t < 4; t++)
#pragma unroll
    for (int u = 0; u < 4; u++)
#pragma unroll
      for (int r = 0; r < 4; r++)
        red[wv][t * 16 + q * 4 + r][u * 16 + i16] = acc[t][u][r];
#pragma unroll
  for (int t = 0; t < 4; t++) ksl[wv][q][t * 16 + i16] = ks[t];
  __syncthreads();
  int d = tid >> 2, mg = (tid & 3) * 16;
#pragma unroll
  for (int c = 0; c < 4; c++) {
    int m = mg + c * 4;
    f32x4 o;
#pragma unroll
    for (int r = 0; r < 4; r++)
      o[r] = red[0][d][m + r] + red[1][d][m + r] + red[2][d][m + r] + red[3][d][m + r];
    *(f32x4*)(part + ((size_t)(chunk * 64 + bh) * 64 + d) * 64 + m) = o;
  }
  if (tid < 64) {
    float s = 0.f;
#pragma unroll
    for (int w2 = 0; w2 < 4; w2++)
#pragma unroll
      for (int q2 = 0; q2 < 4; q2++) s += ksl[w2][q2][tid];
    ksumP[chunk * 4096 + bh * 64 + tid] = s;
  }
}

// ---------------- finalize: KVt (bf16, [bh][m][d]) + Ksum ----------------
__global__ __launch_bounds__(256) void kv_finalize(const float* __restrict__ part,
                                                   const float* __restrict__ ksumP,
                                                   u16* __restrict__ KVt,
                                                   float* __restrict__ Ksum) {
  int bh = blockIdx.x, tid = threadIdx.x;
  for (int e = tid; e < 4096; e += 256) {
    int d = e >> 6, m = e & 63;
    float s = part[((size_t)(0 * 64 + bh) * 64 + d) * 64 + m]
            + part[((size_t)(1 * 64 + bh) * 64 + d) * 64 + m]
            + part[((size_t)(2 * 64 + bh) * 64 + d) * 64 + m]
            + part[((size_t)(3 * 64 + bh) * 64 + d) * 64 + m];
    KVt[(size_t)bh * 4096 + m * 64 + d] = f2bf(s);
  }
  if (tid < 64) {
    float s = ksumP[0 * 4096 + bh * 64 + tid] + ksumP[1 * 4096 + bh * 64 + tid]
            + ksumP[2 * 4096 + bh * 64 + tid] + ksumP[3 * 4096 + bh * 64 + tid];
    Ksum[bh * 64 + tid] = s;
  }
}

// ---------------- V_new = (phi_q @ KV) * Z, LDS-transpose store ----------------
__global__ __launch_bounds__(256) void vnew_kernel(const u16* __restrict__ phiq,
                                                   const u16* __restrict__ KVt,
                                                   const float* __restrict__ Ksum,
                                                   u16* __restrict__ Vnew) {
  int bh = blockIdx.x >> 5, lt = blockIdx.x & 31;
  int b = bh >> 4, h = bh & 15;
  int tid = threadIdx.x, lane = tid & 63, wv = tid >> 6;
  int i16 = lane & 15, q = lane >> 4;
  int waveM = wv & 1, waveL = wv >> 1;

  __shared__ float Zs[128];
  __shared__ float Pp[128][2];
  __shared__ u16 T[128 * 72];
  {
    int l = tid >> 1, half = tid & 1;
    const u16* pr = phiq + (size_t)(b * SL + lt * 128 + l) * DM + h * 64 + half * 32;
    float s = 0.f;
    for (int i = 0; i < 32; i += 8) {
      short8 v8 = *(const short8*)(pr + i);
#pragma unroll
      for (int j = 0; j < 8; j++) s += bf2f((u16)v8[j]) * Ksum[bh * 64 + half * 32 + i + j];
    }
    Pp[l][half] = s;
  }
  __syncthreads();
  if (tid < 128) Zs[tid] = 1.0f / (Pp[tid][0] + Pp[tid][1] + 1e-5f);
  __syncthreads();

  f32x4 acc[2][4] = {};
#pragma unroll
  for (int step = 0; step < 2; step++) {
    int d0 = step * 32 + q * 8;
    short8 af[2], bfr[4];
#pragma unroll
    for (int t = 0; t < 2; t++) {
      int m = waveM * 32 + t * 16 + i16;
      af[t] = *(const short8*)(KVt + (size_t)bh * 4096 + m * 64 + d0);
    }
#pragma unroll
    for (int u = 0; u < 4; u++) {
      int l = lt * 128 + waveL * 64 + u * 16 + i16;
      bfr[u] = *(const short8*)(phiq + (size_t)(b * SL + l) * DM + h * 64 + d0);
    }
#pragma unroll
    for (int t = 0; t < 2; t++)
#pragma unroll
      for (int u = 0; u < 4; u++)
        acc[t][u] = __builtin_amdgcn_mfma_f32_16x16x32_bf16(af[t], bfr[u], acc[t][u], 0, 0, 0);
  }

#pragma unroll
  for (int t = 0; t < 2; t++) {
#pragma unroll
    for (int u = 0; u < 4; u++) {
      int cI = waveL * 64 + u * 16 + i16;           // l
      int nI = waveM * 32 + t * 16 + q * 4;         // n local
      float z = Zs[cI];
      u16x4 o;
#pragma unroll
      for (int r = 0; r < 4; r++) o[r] = f2bf(acc[t][u][r] * z);
      *(u16x4*)(T + cI * 72 + nI) = o;
    }
  }
  __syncthreads();
  {
    const int Rl = tid >> 3, j = tid & 7;
#pragma unroll
    for (int p = 0; p < 4; p++) {
      int R = p * 32 + Rl;
      short8 v8 = *(const short8*)(T + R * 72 + j * 8);
      *(short8*)(Vnew + (size_t)(b * SL + lt * 128 + R) * DM + h * 64 + j * 8) = v8;
    }
  }
}

extern "C" void kernel_launch(void* const* d_in, const int* in_sizes, int n_in,
                              void* d_out, int out_size, void* d_ws, size_t ws_size,
                              hipStream_t stream) {
  const float* Qf = (const float*)d_in[0];
  const float* WQ = (const float*)d_in[1];
  const float* bQ = (const float*)d_in[2];
  const float* WK = (const float*)d_in[3];
  const float* bK = (const float*)d_in[4];
  const float* WV = (const float*)d_in[5];
  const float* bV = (const float*)d_in[6];
  const float* WO = (const float*)d_in[7];
  const float* bO = (const float*)d_in[8];

  const size_t MB = 1024ull * 1024ull;
  char* ws = (char*)d_ws;
  u16* Qbf     = (u16*)(ws + 0);          // 32MB; reused as Vnew
  u16* Vnew    = (u16*)(ws + 0);
  u16* Wqkv    = (u16*)(ws + 32 * MB);    // 6MB
  u16* Wobf    = (u16*)(ws + 38 * MB);    // 2MB
  float* biasQKV = (float*)(ws + 40 * MB);// 12KB
  u16* phiq    = (u16*)(ws + 41 * MB);    // 32MB
  u16* phiKT   = (u16*)(ws + 73 * MB);    // 32MB [b][h][d][l]
  u16* vT      = (u16*)(ws + 105 * MB);   // 32MB [b][h][m][l]
  u16* KVt     = (u16*)(ws + 137 * MB);   // 512KB [bh][m][d]
  float* Ksum  = (float*)(ws + 138 * MB); // 16KB
  float* part  = (float*)(ws + 139 * MB); // 4MB
  float* ksumP = (float*)(ws + 143 * MB); // 64KB

  cvt_all<<<20492, 256, 0, stream>>>(Qf, WQ, WK, WV, WO, bQ, bK, bV,
                                     Qbf, Wqkv, Wobf, biasQKV);

  gemm_qkv<<<3072, 256, 0, stream>>>(Qbf, Wqkv, biasQKV, phiq, phiKT, vT);

  kv_partial<<<256, 256, 0, stream>>>(phiKT, vT, part, ksumP);
  kv_finalize<<<64, 256, 0, stream>>>(part, ksumP, KVt, Ksum);

  vnew_kernel<<<2048, 256, 0, stream>>>(phiq, KVt, Ksum, Vnew);

  gemm_out<<<1024, 256, 0, stream>>>(Vnew, Wobf, bO, (float*)d_out);
}